// Round 8
// baseline (158.739 us; speedup 1.0000x reference)
//
#include <hip/hip_runtime.h>
#include <hip/hip_bf16.h>

// MPNNConv restructured:
//   s[n] = h[n] @ W1[0:128] + b1 (f32 swz), g[n] = h[n] @ W1[128:256] (bf16 swz, L2-resident)
//   Hsum[n] = sum_{e: rows[e]=n} relu(s[n] + g[cols[e]] + ef[e] @ W1e)   (K=32 MFMA, fp8)
//   out[n]  = Hsum[n] @ W2 + deg[n]*b2
// CSR on-device. ef permuted into CSR order as FP8-e4m3 (efb, 32B/edge) so
// layer1 streams its edge payload coalesced; W1e fp8 pre-scaled x16, MFMA acc
// scaled x1/16. rank[] eliminated: permute takes pos = atomicAdd(cur[row]),
// cur emitted by scan as a copy of row_ptr.

typedef __attribute__((ext_vector_type(8))) short bf16x8;
typedef __attribute__((ext_vector_type(4))) float f32x4;

#define ND 128
#define ED 32
#define CH 64            // CSR positions per layer1 chunk
#define INV_WSCALE 0.0625f

__device__ __forceinline__ short f2bf(float x) {
  unsigned int u = __float_as_uint(x);
  unsigned int r = (u + 0x7FFFu + ((u >> 16) & 1u)) >> 16;
  return (short)r;
}

__device__ __forceinline__ float bf2f(short s) {
  return __uint_as_float(((unsigned int)(unsigned short)s) << 16);
}

__device__ __forceinline__ f32x4 bf8lo(bf16x8 v) {
  f32x4 r;
  #pragma unroll
  for (int j = 0; j < 4; ++j) r[j] = bf2f(v[j]);
  return r;
}
__device__ __forceinline__ f32x4 bf8hi(bf16x8 v) {
  f32x4 r;
  #pragma unroll
  for (int j = 0; j < 4; ++j) r[j] = bf2f(v[4 + j]);
  return r;
}

// pack 4 f32 -> 4 fp8 e4m3 bytes (OCP on gfx950)
__device__ __forceinline__ int pk_fp8x4(float a, float b, float c, float d) {
  int w = __builtin_amdgcn_cvt_pk_fp8_f32(a, b, 0, false);
  w = __builtin_amdgcn_cvt_pk_fp8_f32(c, d, w, true);
  return w;
}

// swizzled offset within a 128-wide row for col c (c = ct*16 + cc)
__device__ __forceinline__ int swz(int c) {
  int ct = c >> 4, cc = c & 15;
  return (ct >> 2) * 64 + (cc >> 2) * 16 + (ct & 3) * 4 + (cc & 3);
}

// --- fused: weight pre-layouts (blocks [0,128)) + hist/rc (rest) ---
__global__ __launch_bounds__(256) void prep_hist_kernel(
    const float* __restrict__ W1, const float* __restrict__ W2,
    const void* __restrict__ ei, int* __restrict__ counts,
    unsigned int* __restrict__ rc, short* __restrict__ w12t,
    long long* __restrict__ w1eA8, short* __restrict__ w2t, int E) {
  int b = blockIdx.x;
  if (b < 128) {
    int t = b * 256 + threadIdx.x;
    if (t < 256 * 128) {  // w12t[n'][k]
      int np = t >> 7, k = t & 127;
      float v = (np < 128) ? W1[k * 128 + np] : W1[(128 + k) * 128 + (np - 128)];
      w12t[t] = f2bf(v);
    }
    if (t < 128 * 128) {  // w2t[n][k] = W2[k][n]
      int n = t >> 7, k = t & 127;
      w2t[t] = f2bf(W2[k * 128 + n]);
    }
    if (t < 8 * 64) {     // w1eA8[ct][lane]: 8 fp8 of W1e^T (x16 scale)
      int ct = t >> 6, lane = t & 63;
      int li = lane & 15, lg = lane >> 4;
      float v[8];
      #pragma unroll
      for (int j = 0; j < 8; ++j)
        v[j] = W1[(256 + lg * 8 + j) * 128 + ct * 16 + li] * 16.f;
      int lo = pk_fp8x4(v[0], v[1], v[2], v[3]);
      int hi = pk_fp8x4(v[4], v[5], v[6], v[7]);
      w1eA8[ct * 64 + lane] = (long long)(unsigned int)lo |
                              ((long long)(unsigned int)hi << 32);
    }
  } else {
    int e = (b - 128) * 256 + threadIdx.x;
    if (e < E) {
      const unsigned int* u = (const unsigned int*)ei;
      int is64 = 1;
      #pragma unroll
      for (int i = 0; i < 16; ++i)
        if (u[2 * i + 1] != 0u) is64 = 0;   // uniform -> scalar loads
      int r, c;
      if (is64) {
        r = (int)((const long long*)ei)[e];
        c = (int)((const long long*)ei)[(long long)E + e];
      } else {
        r = ((const int*)ei)[e];
        c = ((const int*)ei)[E + e];
      }
      atomicAdd(&counts[r], 1);
      rc[e] = ((unsigned int)r << 16) | (unsigned int)c;   // N,cols < 65536
    }
  }
}

// --- single-block scan: row_ptr (inclusive shifted) + cur = row_ptr copy ---
__global__ __launch_bounds__(1024) void scan_kernel(const int* __restrict__ counts,
                                                    int* __restrict__ row_ptr,
                                                    int* __restrict__ cur, int n) {
  __shared__ int wtot[16];
  int tid = threadIdx.x;
  int lane = tid & 63, w = tid >> 6;
  int base_i = tid * 16;
  int c[16];
  int tot = 0;
  #pragma unroll
  for (int j = 0; j < 16; ++j) {
    int i = base_i + j;
    c[j] = (i < n) ? counts[i] : 0;
    tot += c[j];
  }
  int x = tot;
  #pragma unroll
  for (int d = 1; d < 64; d <<= 1) {
    int t = __shfl_up(x, d);
    if (lane >= d) x += t;
  }
  if (lane == 63) wtot[w] = x;
  __syncthreads();
  if (w == 0) {
    int y = (lane < 16) ? wtot[lane] : 0;
    #pragma unroll
    for (int d = 1; d < 16; d <<= 1) {
      int t = __shfl_up(y, d);
      if (lane >= d) y += t;
    }
    if (lane < 16) wtot[lane] = y;
  }
  __syncthreads();
  int waveoff = (w == 0) ? 0 : wtot[w - 1];
  int run = waveoff + x - tot;  // exclusive prefix
  if (tid == 0) row_ptr[0] = 0;
  #pragma unroll
  for (int j = 0; j < 16; ++j) {
    int i = base_i + j;
    if (i < n) {
      cur[i] = run;            // cur[i] = row_ptr[i]
      run += c[j];
      row_ptr[i + 1] = run;
    }
  }
}

// --- fused: sg GEMM | ef->efb fp8 permute | chunk bounds ---
__global__ __launch_bounds__(256, 4) void scatter_sg_kernel(
    const float* __restrict__ ef, const int* __restrict__ row_ptr,
    int* __restrict__ cur, const unsigned int* __restrict__ rc,
    const float* __restrict__ h, const short* __restrict__ w12t,
    const float* __restrict__ b1, unsigned char* __restrict__ efb,
    unsigned short* __restrict__ ccol, int2* __restrict__ cb,
    float* __restrict__ s2, short* __restrict__ g2, int N, int E, int nchunks) {
  int b = blockIdx.x;
  int SGB = (N + 63) >> 6;
  int SCB = (2 * E + 255) >> 8;
  if (b < SGB) {
    // ---- s = h@W1top + b1 (f32 swz), g = h@W1mid (bf16 swz)
    int lane = threadIdx.x & 63, w = threadIdx.x >> 6;
    int li = lane & 15, lg = lane >> 4;
    int base = b * 64 + w * 16;
    int rowm = base + li;
    if (rowm >= N) rowm = N - 1;
    float breg[8];
    #pragma unroll
    for (int nt = 0; nt < 8; ++nt) breg[nt] = b1[nt * 16 + li];
    f32x4 acc[16];
    #pragma unroll
    for (int nt = 0; nt < 16; ++nt) acc[nt] = (f32x4){0.f, 0.f, 0.f, 0.f};
    #pragma unroll
    for (int kc = 0; kc < 4; ++kc) {
      f32x4 f0 = *(const f32x4*)(h + (size_t)rowm * ND + kc * 32 + lg * 8);
      f32x4 f1 = *(const f32x4*)(h + (size_t)rowm * ND + kc * 32 + lg * 8 + 4);
      bf16x8 a;
      #pragma unroll
      for (int j = 0; j < 4; ++j) { a[j] = f2bf(f0[j]); a[4 + j] = f2bf(f1[j]); }
      #pragma unroll
      for (int nt = 0; nt < 16; ++nt) {
        bf16x8 bb = *(const bf16x8*)(w12t + (nt * 16 + li) * 128 + kc * 32 + lg * 8);
        acc[nt] = __builtin_amdgcn_mfma_f32_16x16x32_bf16(a, bb, acc[nt], 0, 0, 0);
      }
    }
    #pragma unroll
    for (int nt = 0; nt < 16; ++nt)
      #pragma unroll
      for (int r = 0; r < 4; ++r) {
        int row = base + lg * 4 + r;
        if (row < N) {
          if (nt < 8) {
            s2[(size_t)row * 128 + swz(nt * 16 + li)] = acc[nt][r] + breg[nt];
          } else {
            g2[(size_t)row * 128 + swz((nt - 8) * 16 + li)] = f2bf(acc[nt][r]);
          }
        }
      }
  } else if (b < SGB + SCB) {
    // ---- permute: 2 threads/edge; coalesced ef read, fp8 convert, 16B write
    int gt = (b - SGB) * 256 + threadIdx.x;
    int e = gt >> 1, part = gt & 1;
    if (e < E) {
      unsigned int p = rc[e];
      int r = (int)(p >> 16), c = (int)(p & 0xffffu);
      int pos0 = 0;
      if (part == 0) pos0 = atomicAdd(&cur[r], 1);
      int lane = threadIdx.x & 63;
      int pos = __shfl(pos0, lane - part);
      const float* ep = ef + (size_t)e * ED + part * 16;
      f32x4 x0 = *(const f32x4*)(ep);
      f32x4 x1 = *(const f32x4*)(ep + 4);
      f32x4 x2 = *(const f32x4*)(ep + 8);
      f32x4 x3 = *(const f32x4*)(ep + 12);
      int4 ob;
      ob.x = pk_fp8x4(x0[0], x0[1], x0[2], x0[3]);
      ob.y = pk_fp8x4(x1[0], x1[1], x1[2], x1[3]);
      ob.z = pk_fp8x4(x2[0], x2[1], x2[2], x2[3]);
      ob.w = pk_fp8x4(x3[0], x3[1], x3[2], x3[3]);
      *(int4*)(efb + (size_t)pos * ED + part * 16) = ob;
      if (part == 0) ccol[pos] = (unsigned short)c;
    }
  } else {
    // ---- chunk bounds
    int k = (b - SGB - SCB) * 256 + threadIdx.x;
    if (k < nchunks) {
      int t0 = k * CH, t1 = t0 + CH;
      int lo = 0, hi = N;
      while (lo < hi) { int mid = (lo + hi) >> 1; if (row_ptr[mid] < t0) lo = mid + 1; else hi = mid; }
      int na = lo;
      hi = N;
      while (lo < hi) { int mid = (lo + hi) >> 1; if (row_ptr[mid] < t1) lo = mid + 1; else hi = mid; }
      cb[k] = make_int2(na, lo);
    }
  }
}

// --- layer 1 + segment reduce: chunk-balanced, 2 waves/block (col halves),
//     efb(fp8)/ccol streamed coalesced, g gathered from L2 ---
__global__ __launch_bounds__(128, 4) void layer1_kernel(
    const float* __restrict__ s2, const short* __restrict__ g2,
    const unsigned char* __restrict__ efb, const unsigned short* __restrict__ ccol,
    const long long* __restrict__ w1eA8, const int* __restrict__ row_ptr,
    const int2* __restrict__ cb, float* __restrict__ hsum) {
  int2 bounds = cb[blockIdx.x];
  int na = bounds.x, nb = bounds.y;
  if (na >= nb) return;
  int lane = threadIdx.x & 63;
  int w = threadIdx.x >> 6;  // col half 0/1
  int li = lane & 15, lg = lane >> 4;

  long long wa[4];
  #pragma unroll
  for (int nt = 0; nt < 4; ++nt)
    wa[nt] = w1eA8[(w * 4 + nt) * 64 + lane];

  for (int n = na; n < nb; ++n) {
    int rp = row_ptr[n], rpe = row_ptr[n + 1];
    int deg = rpe - rp;
    f32x4 sreg[4];
    #pragma unroll
    for (int nt = 0; nt < 4; ++nt)
      sreg[nt] = *(const f32x4*)(s2 + (size_t)n * 128 + w * 64 + lg * 16 + nt * 4);
    f32x4 psum[4];
    #pragma unroll
    for (int nt = 0; nt < 4; ++nt) psum[nt] = (f32x4){0.f, 0.f, 0.f, 0.f};

    int ntiles = (deg + 15) >> 4;
    int last = rpe - 1;
    auto ldpos = [&](int t) {
      int p = rp + t * 16 + li;
      return p > last ? last : p;
    };

    int pA = ldpos(0), pB = ldpos(1);
    int cA = ccol[pA], cB = ccol[pB];
    long long eA = *(const long long*)(efb + (size_t)pA * ED + lg * 8);
    long long eB = *(const long long*)(efb + (size_t)pB * ED + lg * 8);
    const short* gpA = g2 + (size_t)cA * 128 + w * 64 + lg * 16;
    bf16x8 gA0 = *(const bf16x8*)gpA;
    bf16x8 gA1 = *(const bf16x8*)(gpA + 8);

    for (int t = 0; t < ntiles; ++t) {
      const short* gpB = g2 + (size_t)cB * 128 + w * 64 + lg * 16;
      bf16x8 gB0 = *(const bf16x8*)gpB;
      bf16x8 gB1 = *(const bf16x8*)(gpB + 8);
      int pC = ldpos(t + 2);
      int cC = ccol[pC];
      long long eC = *(const long long*)(efb + (size_t)pC * ED + lg * 8);
      // compute tile t  (W1e was scaled x16 -> acc * 1/16)
      f32x4 a0 = __builtin_amdgcn_mfma_f32_16x16x32_fp8_fp8(wa[0], eA, (f32x4){0.f,0.f,0.f,0.f}, 0, 0, 0);
      f32x4 a1 = __builtin_amdgcn_mfma_f32_16x16x32_fp8_fp8(wa[1], eA, (f32x4){0.f,0.f,0.f,0.f}, 0, 0, 0);
      f32x4 a2 = __builtin_amdgcn_mfma_f32_16x16x32_fp8_fp8(wa[2], eA, (f32x4){0.f,0.f,0.f,0.f}, 0, 0, 0);
      f32x4 a3 = __builtin_amdgcn_mfma_f32_16x16x32_fp8_fp8(wa[3], eA, (f32x4){0.f,0.f,0.f,0.f}, 0, 0, 0);
      if ((t * 16 + li) < deg) {
        f32x4 g0 = bf8lo(gA0), g1 = bf8hi(gA0), g2v = bf8lo(gA1), g3 = bf8hi(gA1);
        #pragma unroll
        for (int r = 0; r < 4; ++r) {
          float v0 = fmaf(a0[r], INV_WSCALE, sreg[0][r] + g0[r]);
          float v1 = fmaf(a1[r], INV_WSCALE, sreg[1][r] + g1[r]);
          float v2 = fmaf(a2[r], INV_WSCALE, sreg[2][r] + g2v[r]);
          float v3 = fmaf(a3[r], INV_WSCALE, sreg[3][r] + g3[r]);
          psum[0][r] += (v0 > 0.f ? v0 : 0.f);
          psum[1][r] += (v1 > 0.f ? v1 : 0.f);
          psum[2][r] += (v2 > 0.f ? v2 : 0.f);
          psum[3][r] += (v3 > 0.f ? v3 : 0.f);
        }
      }
      cB = cC; eA = eB; eB = eC;
      gA0 = gB0; gA1 = gB1;
    }

    #pragma unroll
    for (int nt = 0; nt < 4; ++nt)
      #pragma unroll
      for (int r = 0; r < 4; ++r) {
        float v = psum[nt][r];
        v += __shfl_xor(v, 1);
        v += __shfl_xor(v, 2);
        v += __shfl_xor(v, 4);
        v += __shfl_xor(v, 8);
        psum[nt][r] = v;
      }
    if (li == 0) {
      #pragma unroll
      for (int nt = 0; nt < 4; ++nt)
        *(f32x4*)(hsum + (size_t)n * 128 + w * 64 + nt * 16 + lg * 4) = psum[nt];
    }
  }
}

// --- out = Hsum @ W2 + deg*b2 ; 4 waves x 16 rows per block ---
__global__ __launch_bounds__(256) void out_kernel(const float* __restrict__ hsum,
                                                  const short* __restrict__ w2t,
                                                  const float* __restrict__ b2,
                                                  const int* __restrict__ row_ptr,
                                                  float* __restrict__ out, int N) {
  int lane = threadIdx.x & 63, w = threadIdx.x >> 6;
  int li = lane & 15, lg = lane >> 4;
  int base = blockIdx.x * 64 + w * 16;
  int rowm = base + li;
  if (rowm >= N) rowm = N - 1;
  float breg[8];
  #pragma unroll
  for (int nt = 0; nt < 8; ++nt) breg[nt] = b2[nt * 16 + li];
  f32x4 acc[8];
  #pragma unroll
  for (int nt = 0; nt < 8; ++nt) acc[nt] = (f32x4){0.f, 0.f, 0.f, 0.f};
  #pragma unroll
  for (int kc = 0; kc < 4; ++kc) {
    f32x4 f0 = *(const f32x4*)(hsum + (size_t)rowm * 128 + kc * 32 + lg * 8);
    f32x4 f1 = *(const f32x4*)(hsum + (size_t)rowm * 128 + kc * 32 + lg * 8 + 4);
    bf16x8 a;
    #pragma unroll
    for (int j = 0; j < 4; ++j) { a[j] = f2bf(f0[j]); a[4 + j] = f2bf(f1[j]); }
    #pragma unroll
    for (int nt = 0; nt < 8; ++nt) {
      bf16x8 bb = *(const bf16x8*)(w2t + (nt * 16 + li) * 128 + kc * 32 + lg * 8);
      acc[nt] = __builtin_amdgcn_mfma_f32_16x16x32_bf16(a, bb, acc[nt], 0, 0, 0);
    }
  }
  #pragma unroll
  for (int r = 0; r < 4; ++r) {
    int row = base + lg * 4 + r;
    if (row < N) {
      float dg = (float)(row_ptr[row + 1] - row_ptr[row]);
      #pragma unroll
      for (int nt = 0; nt < 8; ++nt)
        out[(size_t)row * 128 + nt * 16 + li] = acc[nt][r] + dg * breg[nt];
    }
  }
}

extern "C" void kernel_launch(void* const* d_in, const int* in_sizes, int n_in,
                              void* d_out, int out_size, void* d_ws, size_t ws_size,
                              hipStream_t stream) {
  const float* h  = (const float*)d_in[0];
  const void*  ei = d_in[1];
  const float* ef = (const float*)d_in[2];
  const float* W1 = (const float*)d_in[4];
  const float* b1 = (const float*)d_in[5];
  const float* W2 = (const float*)d_in[6];
  const float* b2 = (const float*)d_in[7];
  float* out = (float*)d_out;
  int N = in_sizes[0] / ND;
  int E = in_sizes[2] / ED;
  int nchunks = (E + CH - 1) / CH;

  char* ws = (char*)d_ws;
  size_t off = 0;
  auto alloc = [&](size_t bytes) {
    size_t o = off;
    off = (off + bytes + 255) & ~(size_t)255;
    return o;
  };
  int*            counts  = (int*)(ws + alloc((size_t)N * 4));
  int*            row_ptr = (int*)(ws + alloc((size_t)(N + 1) * 4));
  int*            cur     = (int*)(ws + alloc((size_t)N * 4));
  unsigned int*   rc      = (unsigned int*)(ws + alloc((size_t)E * 4));
  short*          w12t    = (short*)(ws + alloc(256 * 128 * 2));
  long long*      w1eA8   = (long long*)(ws + alloc(8 * 64 * 8));
  short*          w2t     = (short*)(ws + alloc(128 * 128 * 2));
  float*          s2      = (float*)(ws + alloc((size_t)N * 128 * 4));
  short*          g2      = (short*)(ws + alloc((size_t)N * 128 * 2));
  float*          hsumb   = (float*)(ws + alloc((size_t)N * 128 * 4));
  unsigned char*  efb     = (unsigned char*)(ws + alloc((size_t)E * ED));
  unsigned short* ccol    = (unsigned short*)(ws + alloc((size_t)E * 2));
  int2*           cbb     = (int2*)(ws + alloc((size_t)nchunks * 8));

  int SGB = (N + 63) >> 6;
  int SCB = (2 * E + 255) >> 8;
  int CBB = (nchunks + 255) >> 8;

  hipMemsetAsync(counts, 0, (size_t)N * 4, stream);
  prep_hist_kernel<<<128 + (E + 255) / 256, 256, 0, stream>>>(
      W1, W2, ei, counts, rc, w12t, w1eA8, w2t, E);
  scan_kernel<<<1, 1024, 0, stream>>>(counts, row_ptr, cur, N);
  scatter_sg_kernel<<<SGB + SCB + CBB, 256, 0, stream>>>(
      ef, row_ptr, cur, rc, h, w12t, b1, efb, ccol, cbb, s2, g2, N, E, nchunks);
  layer1_kernel<<<nchunks, 128, 0, stream>>>(s2, g2, efb, ccol, w1eA8, row_ptr, cbb, hsumb);
  out_kernel<<<(N + 63) / 64, 256, 0, stream>>>(hsumb, w2t, b2, row_ptr, out, N);
}